// Round 22
// baseline (99.047 us; speedup 1.0000x reference)
//
#include <hip/hip_runtime.h>

#define S_ 2304   // 48*48

typedef unsigned short u16;
typedef unsigned int u32;
typedef __attribute__((ext_vector_type(8))) short bf16x8;
typedef __attribute__((ext_vector_type(4))) float f32x4;

static __device__ __forceinline__ u16 f2bf(float x) {
  union { float f; unsigned u; } v; v.f = x;
  unsigned r = v.u + 0x7FFFu + ((v.u >> 16) & 1u);
  return (u16)(r >> 16);
}
static __device__ __forceinline__ float bf2f(u16 h) {
  union { unsigned u; float f; } v; v.u = ((unsigned)h) << 16; return v.f;
}
static __device__ __forceinline__ float bflo(unsigned p) {
  union { unsigned u; float f; } v; v.u = p << 16; return v.f;
}
static __device__ __forceinline__ float bfhi(unsigned p) {
  union { unsigned u; float f; } v; v.u = p & 0xFFFF0000u; return v.f;
}

// ---------------------------------------------------------------------------
// Prep: weight split only (x-transpose deleted -- gemm_qkv reads x directly).
// blocks 0..191 -> rcv_w, 192..255 -> proj_w.
// ---------------------------------------------------------------------------
__global__ __launch_bounds__(256) void prep_kernel(
    const float* __restrict__ w0, u16* __restrict__ wh0, u16* __restrict__ wl0,
    const float* __restrict__ w1, u16* __restrict__ wh1, u16* __restrict__ wl1)
{
  const int bid = blockIdx.x;
  const int tid = threadIdx.x;
  const float* w; u16 *wh, *wl; int id;
  if (bid < 192) { w = w0; wh = wh0; wl = wl0; id = bid * 256 + tid; }
  else { w = w1; wh = wh1; wl = wl1; id = (bid - 192) * 256 + tid; }
  float4 v = ((const float4*)w)[id];
  short4 h, l;
  float f[4] = {v.x, v.y, v.z, v.w};
  u16 hh[4], ll[4];
#pragma unroll
  for (int q = 0; q < 4; q++) {
    hh[q] = f2bf(f[q]);
    ll[q] = f2bf(f[q] - bf2f(hh[q]));
  }
  h.x = hh[0]; h.y = hh[1]; h.z = hh[2]; h.w = hh[3];
  l.x = ll[0]; l.y = ll[1]; l.z = ll[2]; l.w = ll[3];
  ((short4*)wh)[id] = h;
  ((short4*)wl)[id] = l;
}

// ---------------------------------------------------------------------------
// QKV GEMM: Out = (Wh+Wl)*bf16(x), M=768. BN=64 (gemm_n64 twin): 1728 blocks
// = 6.75/CU. B loaded DIRECTLY from x fp32 [k][s] (f2bf in reg, 4x64B
// segments per instr, kstep-ahead prefetch -- r21-proven LOAD_B pattern).
// Epilogue writes PAIR-PACKED bf16 qkvP (r18-proven).
// ---------------------------------------------------------------------------
__global__ __launch_bounds__(256) void gemm_qkv_kernel(
    const u16* __restrict__ Wh, const u16* __restrict__ Wl,
    const float* __restrict__ bias,
    const float* __restrict__ x, u32* __restrict__ qkvP)
{
  __shared__ u16 wAh[2][64 * 40];
  __shared__ u16 wAl[2][64 * 40];
  const int MB = 12;
  const int xcd = blockIdx.x & 7;
  const int idx = blockIdx.x >> 3;          // 0..215
  const int g = xcd * 18 + idx / MB;        // 0..143 = (nb, b)
  const int mb = idx % MB;
  const int nb = g % 36, b = g / 36;
  const int m0 = mb * 64, n0 = nb * 64;
  const int tid = threadIdx.x;
  const int wv = tid >> 6, lane = tid & 63;
  const int wm = wv >> 1, wsd = wv & 1;
  const int lr = lane & 15, lg = lane >> 4;

  const float* xb = x + (size_t)b * 256 * S_;
  const int s0 = n0 + wsd * 32;

  f32x4 acc[2][2];
#pragma unroll
  for (int mt = 0; mt < 2; mt++)
#pragma unroll
    for (int nt = 0; nt < 2; nt++) acc[mt][nt] = (f32x4){0.f, 0.f, 0.f, 0.f};

#define STAGE_W(t, buf)                                                      \
  {                                                                          \
    _Pragma("unroll")                                                        \
    for (int r = 0; r < 2; r++) {                                            \
      int id = tid + r * 256;                                                \
      int m = id >> 3, k4 = (id & 7) * 4;                                    \
      *(short4*)&wAh[buf][m * 40 + k4] =                                     \
          *(const short4*)&Wh[(size_t)(m0 + m) * 256 + (t) * 32 + k4];       \
      *(short4*)&wAl[buf][m * 40 + k4] =                                     \
          *(const short4*)&Wl[(size_t)(m0 + m) * 256 + (t) * 32 + k4];       \
    }                                                                        \
  }

#define LOAD_B(t, dst)                                                       \
  {                                                                          \
    _Pragma("unroll")                                                        \
    for (int nt = 0; nt < 2; nt++) {                                         \
      int s = s0 + nt * 16 + lr;                                             \
      _Pragma("unroll")                                                      \
      for (int e = 0; e < 8; e++)                                            \
        dst[nt][e] = (short)f2bf(xb[(size_t)((t) * 32 + lg * 8 + e) * S_ + s]); \
    }                                                                        \
  }

  STAGE_W(0, 0);
  bf16x8 cb[2];
  LOAD_B(0, cb);
  __syncthreads();

  for (int t = 0; t < 8; t++) {
    int buf = t & 1;
    if (t < 7) STAGE_W(t + 1, buf ^ 1);

    bf16x8 nbv[2];
    if (t < 7) {
      LOAD_B(t + 1, nbv);
    } else {
#pragma unroll
      for (int nt = 0; nt < 2; nt++)
#pragma unroll
        for (int e = 0; e < 8; e++) nbv[nt][e] = 0;
    }

    bf16x8 ah[2], al[2];
#pragma unroll
    for (int mt = 0; mt < 2; mt++) {
      ah[mt] = *(const bf16x8*)&wAh[buf][(wm * 32 + mt * 16 + lr) * 40 + lg * 8];
      al[mt] = *(const bf16x8*)&wAl[buf][(wm * 32 + mt * 16 + lr) * 40 + lg * 8];
    }
#pragma unroll
    for (int mt = 0; mt < 2; mt++)
#pragma unroll
      for (int nt = 0; nt < 2; nt++) {
        acc[mt][nt] = __builtin_amdgcn_mfma_f32_16x16x32_bf16(ah[mt], cb[nt], acc[mt][nt], 0, 0, 0);
        acc[mt][nt] = __builtin_amdgcn_mfma_f32_16x16x32_bf16(al[mt], cb[nt], acc[mt][nt], 0, 0, 0);
      }
    __syncthreads();
#pragma unroll
    for (int nt = 0; nt < 2; nt++) cb[nt] = nbv[nt];
  }

  // epilogue: pack pairs of consecutive planes into u32 (r18 layout)
#pragma unroll
  for (int mt = 0; mt < 2; mt++) {
    int mb_ = m0 + wm * 32 + mt * 16 + lg * 4;   // 4 consecutive planes
    float4 b4 = *(const float4*)&bias[mb_];
    int head = mb_ / 96, pl = mb_ % 96;
    size_t rowoff = ((size_t)(b * 8 + head) * 48 + (pl >> 1)) * S_;
#pragma unroll
    for (int nt = 0; nt < 2; nt++) {
      int s = s0 + nt * 16 + lr;
      u16 h0 = f2bf(acc[mt][nt][0] + b4.x);
      u16 h1 = f2bf(acc[mt][nt][1] + b4.y);
      u16 h2 = f2bf(acc[mt][nt][2] + b4.z);
      u16 h3 = f2bf(acc[mt][nt][3] + b4.w);
      qkvP[rowoff + s]      = (u32)h0 | ((u32)h1 << 16);
      qkvP[rowoff + S_ + s] = (u32)h2 | ((u32)h3 << 16);
    }
  }
#undef STAGE_W
#undef LOAD_B
}

// ---------------------------------------------------------------------------
// Proj GEMM (r21-proven, unchanged): BN=64, B direct from packed yP.
// ---------------------------------------------------------------------------
__global__ __launch_bounds__(256) void gemm_n64_kernel(
    const u16* __restrict__ Wh, const u16* __restrict__ Wl,
    const float* __restrict__ bias,
    const u32* __restrict__ yP, float* __restrict__ Out)
{
  __shared__ u16 wAh[2][64 * 40];
  __shared__ u16 wAl[2][64 * 40];
  const int M = 256, MB = 4;
  const int xcd = blockIdx.x & 7;
  const int idx = blockIdx.x >> 3;
  const int g = xcd * 18 + idx / MB;
  const int mb = idx % MB;
  const int nb = g % 36, b = g / 36;
  const int m0 = mb * 64, n0 = nb * 64;
  const int tid = threadIdx.x;
  const int wv = tid >> 6, lane = tid & 63;
  const int wm = wv >> 1, wsd = wv & 1;
  const int lr = lane & 15, lg = lane >> 4;

  const u32* yb = yP + (size_t)b * 256 * S_;
  const int s0 = n0 + wsd * 32;

  f32x4 acc[2][2];
#pragma unroll
  for (int mt = 0; mt < 2; mt++)
#pragma unroll
    for (int nt = 0; nt < 2; nt++) acc[mt][nt] = (f32x4){0.f, 0.f, 0.f, 0.f};

#define STAGE_W(t, buf)                                                      \
  {                                                                          \
    _Pragma("unroll")                                                        \
    for (int r = 0; r < 2; r++) {                                            \
      int id = tid + r * 256;                                                \
      int m = id >> 3, k4 = (id & 7) * 4;                                    \
      *(short4*)&wAh[buf][m * 40 + k4] =                                     \
          *(const short4*)&Wh[(size_t)(m0 + m) * 256 + (t) * 32 + k4];       \
      *(short4*)&wAl[buf][m * 40 + k4] =                                     \
          *(const short4*)&Wl[(size_t)(m0 + m) * 256 + (t) * 32 + k4];       \
    }                                                                        \
  }

#define LOAD_B(t, dst)                                                       \
  {                                                                          \
    _Pragma("unroll")                                                        \
    for (int nt = 0; nt < 2; nt++) {                                         \
      int s = s0 + nt * 16 + lr;                                             \
      _Pragma("unroll")                                                      \
      for (int e = 0; e < 8; e++)                                            \
        dst[nt][e] = yb[(size_t)((t) * 32 + lg * 8 + e) * S_ + s];           \
    }                                                                        \
  }

  STAGE_W(0, 0);
  u32 cb[2][8];
  LOAD_B(0, cb);
  __syncthreads();

  for (int t = 0; t < 8; t++) {
    int buf = t & 1;
    if (t < 7) STAGE_W(t + 1, buf ^ 1);

    u32 nbv[2][8];
    if (t < 7) {
      LOAD_B(t + 1, nbv);
    } else {
#pragma unroll
      for (int nt = 0; nt < 2; nt++)
#pragma unroll
        for (int e = 0; e < 8; e++) nbv[nt][e] = 0;
    }

    bf16x8 ah[2], al[2];
#pragma unroll
    for (int mt = 0; mt < 2; mt++) {
      ah[mt] = *(const bf16x8*)&wAh[buf][(wm * 32 + mt * 16 + lr) * 40 + lg * 8];
      al[mt] = *(const bf16x8*)&wAl[buf][(wm * 32 + mt * 16 + lr) * 40 + lg * 8];
    }
    bf16x8 bh[2], bl[2];
#pragma unroll
    for (int nt = 0; nt < 2; nt++)
#pragma unroll
      for (int e = 0; e < 8; e++) {
        bh[nt][e] = (short)(cb[nt][e] & 0xffffu);
        bl[nt][e] = (short)(cb[nt][e] >> 16);
      }
#pragma unroll
    for (int mt = 0; mt < 2; mt++)
#pragma unroll
      for (int nt = 0; nt < 2; nt++) {
        acc[mt][nt] = __builtin_amdgcn_mfma_f32_16x16x32_bf16(ah[mt], bh[nt], acc[mt][nt], 0, 0, 0);
        acc[mt][nt] = __builtin_amdgcn_mfma_f32_16x16x32_bf16(ah[mt], bl[nt], acc[mt][nt], 0, 0, 0);
        acc[mt][nt] = __builtin_amdgcn_mfma_f32_16x16x32_bf16(al[mt], bh[nt], acc[mt][nt], 0, 0, 0);
      }
    __syncthreads();
#pragma unroll
    for (int nt = 0; nt < 2; nt++)
#pragma unroll
      for (int e = 0; e < 8; e++) cb[nt][e] = nbv[nt][e];
  }

  float* ob = Out + (size_t)b * M * S_;
#pragma unroll
  for (int mt = 0; mt < 2; mt++) {
    float4 b4 = *(const float4*)&bias[m0 + wm * 32 + mt * 16 + lg * 4];
    float bv[4] = {b4.x, b4.y, b4.z, b4.w};
#pragma unroll
    for (int nt = 0; nt < 2; nt++) {
      int s = n0 + wsd * 32 + nt * 16 + lr;
#pragma unroll
      for (int r = 0; r < 4; r++) {
        int m = m0 + wm * 32 + mt * 16 + lg * 4 + r;
        ob[(size_t)m * S_ + s] = acc[mt][nt][r] + bv[r];
      }
    }
  }
#undef STAGE_W
#undef LOAD_B
}

// ---------------------------------------------------------------------------
// Scores: packed u32 operands, dbuf (r21 structure), NO max-subtraction --
// scores are bounded (|S| <~ 5 << 88), so exp is computed in the fully
// parallel COMPUTE phase and the reduce phase is sum-only.
// 1024 blocks: 0..511 ROW, 512..1023 COL.
// ---------------------------------------------------------------------------
__global__ __launch_bounds__(256) void scores_kernel(
    const u32* __restrict__ qkv, u16* __restrict__ arF, u16* __restrict__ awF)
{
  __shared__ float Sm[2][48 * 49];
  __shared__ float red1[2][48];
  __shared__ u32 rkp[2][8 * 48];
  __shared__ u32 cqp[2][8 * 48], ckp[2][8 * 48];
  const int bid = blockIdx.x;
  const int tid = threadIdx.x;

  if (bid < 512) {
    // ---------------- ROW ----------------
    const int hg = bid & 15, n = (bid >> 4) & 7, b = bid >> 7;
    const u32* base = qkv + (size_t)(b * 8 + n) * 48 * S_;
    u32 rqp[9][8];
#pragma unroll
    for (int k = 0; k < 9; k++) {
      int p = tid + k * 256;
#pragma unroll
      for (int d8 = 0; d8 < 8; d8++)
        rqp[k][d8] = base[(size_t)d8 * S_ + p];
    }
    {
      int h = hg * 3;
      for (int id = tid; id < 384; id += 256)
        rkp[0][id] = base[(size_t)(8 + id / 48) * S_ + h * 48 + (id % 48)];
    }
    __syncthreads();
    for (int hh = 0; hh < 3; hh++) {
      const int buf = hh & 1;
      const int h = hg * 3 + hh;
#pragma unroll
      for (int k = 0; k < 9; k++) {
        int p = tid + k * 256;
        int i = p / 48, w = p % 48;
        float s = 0.f;
#pragma unroll
        for (int d8 = 0; d8 < 8; d8++) {
          u32 a = rqp[k][d8], c = rkp[buf][d8 * 48 + w];
          s += bflo(a) * bflo(c) + bfhi(a) * bfhi(c);
        }
        Sm[buf][i * 49 + w] = __expf(s * 0.25f);
      }
      if (hh < 2) {
        int hn = h + 1;
        for (int id = tid; id < 384; id += 256)
          rkp[buf ^ 1][id] = base[(size_t)(8 + id / 48) * S_ + hn * 48 + (id % 48)];
      }
      __syncthreads();
      if (tid < 192) {
        int w = tid >> 2, e = tid & 3;
        float s = 0.f;
        for (int i = e; i < 48; i += 4) s += Sm[buf][i * 49 + w];
        s += __shfl_xor(s, 1);
        s += __shfl_xor(s, 2);
        red1[buf][w] = 1.0f / s;
      }
      __syncthreads();
      u16* dst = arF + ((size_t)(b * 8 + n) * 48 + h) * 2304;
      for (int id = tid; id < 576; id += 256) {
        int nt = id / 192, rem = id % 192, mt = rem / 64, l = rem % 64;
        int w = nt * 16 + (l & 15);
        int i0 = mt * 16 + ((l >> 4) << 2);
        float rs = red1[buf][w];
        short4 o;
        o.x = (short)f2bf(Sm[buf][(i0 + 0) * 49 + w] * rs);
        o.y = (short)f2bf(Sm[buf][(i0 + 1) * 49 + w] * rs);
        o.z = (short)f2bf(Sm[buf][(i0 + 2) * 49 + w] * rs);
        o.w = (short)f2bf(Sm[buf][(i0 + 3) * 49 + w] * rs);
        *(short4*)&dst[id * 4] = o;
      }
    }
  } else {
    // ---------------- COL ----------------
    const int bid2 = bid - 512;
    const int hg = bid2 & 15, n = (bid2 >> 4) & 7, b = bid2 >> 7;
    const u32* base = qkv + (size_t)(b * 8 + n) * 48 * S_;
    {
      int h = hg * 3;
      for (int id = tid; id < 384; id += 256) {
        cqp[0][id] = base[(size_t)(16 + id / 48) * S_ + h * 48 + (id % 48)];
        ckp[0][id] = base[(size_t)(24 + id / 48) * S_ + h * 48 + (id % 48)];
      }
    }
    __syncthreads();
    for (int hh = 0; hh < 3; hh++) {
      const int buf = hh & 1;
      const int h = hg * 3 + hh;
      for (int id = tid; id < 2304; id += 256) {
        int w = id / 48, j = id % 48;
        float t = 0.f;
#pragma unroll
        for (int d8 = 0; d8 < 8; d8++) {
          u32 c = ckp[buf][d8 * 48 + w], a = cqp[buf][d8 * 48 + j];
          t += bflo(c) * bflo(a) + bfhi(c) * bfhi(a);
        }
        Sm[buf][w * 49 + j] = __expf(t * 0.25f);
      }
      if (hh < 2) {
        int hn = h + 1;
        for (int id = tid; id < 384; id += 256) {
          cqp[buf ^ 1][id] = base[(size_t)(16 + id / 48) * S_ + hn * 48 + (id % 48)];
          ckp[buf ^ 1][id] = base[(size_t)(24 + id / 48) * S_ + hn * 48 + (id % 48)];
        }
      }
      __syncthreads();
      if (tid < 192) {
        int w = tid >> 2, e = tid & 3;
        float s = 0.f;
        for (int j = e; j < 48; j += 4) s += Sm[buf][w * 49 + j];
        s += __shfl_xor(s, 1);
        s += __shfl_xor(s, 2);
        red1[buf][w] = 1.0f / s;
      }
      __syncthreads();
      u16* dst = awF + ((size_t)(b * 8 + n) * 48 + h) * 3072;
      for (int id = tid; id < 384; id += 256) {
        int nt = id / 128, rem = id % 128, ks = rem / 64, l = rem % 64;
        int w = nt * 16 + (l & 15);
        int j0 = ks * 32 + ((l >> 4) << 3);
        float rs = red1[buf][w];
        u16 t8[8];
#pragma unroll
        for (int e = 0; e < 8; e++) {
          int j = j0 + e;
          t8[e] = (j < 48) ? f2bf(Sm[buf][w * 49 + j] * rs) : (u16)0;
        }
        short4 o0, o1;
        o0.x = (short)t8[0]; o0.y = (short)t8[1]; o0.z = (short)t8[2]; o0.w = (short)t8[3];
        o1.x = (short)t8[4]; o1.y = (short)t8[5]; o1.z = (short)t8[6]; o1.w = (short)t8[7];
        *(short4*)&dst[id * 8]     = o0;
        *(short4*)&dst[id * 8 + 4] = o1;
      }
    }
  }
}

// ---------------------------------------------------------------------------
// Main contraction + PE conv (r21-proven, unchanged): packed-v staging,
// packed h|l yP epilogue.
// ---------------------------------------------------------------------------
__global__ __launch_bounds__(256) void attn_main_kernel(
    const u32* __restrict__ qkv, const u16* __restrict__ arF,
    const u16* __restrict__ awF, const float* __restrict__ pe_w,
    const float* __restrict__ pe_b, u32* __restrict__ yP)
{
  __shared__ u16 vA[96 * 72];         // 13824 B
  const int id0 = blockIdx.x;
  const int n = id0 & 7;              // XCD swizzle
  const int rest = id0 >> 3;          // 0..255
  const int b = rest >> 6;
  const int inner = rest & 63;
  const int dchunk = inner >> 2;      // 0..15 (one v-pair each)
  const int hc = inner & 3;
  const int tid = threadIdx.x;
  const int wave = tid >> 6, lane = tid & 63;
  const int dl = wave >> 1, half = wave & 1;
  const int h0 = hc * 12 + half * 6;
  const int lr = lane & 15, lg = lane >> 4;

  for (int id = tid; id < 96 * 24; id += 256) {
    int row = id / 24, col = 48 + id % 24;
    vA[row * 72 + col] = 0;
  }
  const u32* vrow = qkv + ((size_t)(b * 8 + n) * 48 + 32 + dchunk) * S_;
  for (int id = tid; id < 576; id += 256) {
    int i = id / 12, j4 = (id % 12) * 4;
    uint4 v = *(const uint4*)&vrow[i * 48 + j4];
    short4 lo, hi;
    lo.x = (short)(v.x & 0xffff); hi.x = (short)(v.x >> 16);
    lo.y = (short)(v.y & 0xffff); hi.y = (short)(v.y >> 16);
    lo.z = (short)(v.z & 0xffff); hi.z = (short)(v.z >> 16);
    lo.w = (short)(v.w & 0xffff); hi.w = (short)(v.w >> 16);
    *(short4*)&vA[i * 72 + j4] = lo;
    *(short4*)&vA[(48 + i) * 72 + j4] = hi;
  }
  __syncthreads();   // the only barrier

  const size_t bn48 = (size_t)(b * 8 + n) * 48;
  const int c = n * 32 + dchunk * 2 + dl;
  float pw[9];
#pragma unroll
  for (int t = 0; t < 9; t++) pw[t] = pe_w[c * 9 + t];
  const float pb = pe_b[c];
  u32* yg = yP + ((size_t)b * 256 + c) * S_;
  const int vrow0 = dl * 48;

  for (int hh = 0; hh < 6; hh++) {
    int h = h0 + hh;
    const u16* awg = awF + (bn48 + h) * 3072;
    const u16* arg = arF + (bn48 + h) * 2304;

    bf16x8 bf0[3], bf1[3];
#pragma unroll
    for (int nt = 0; nt < 3; nt++) {
      bf0[nt] = *(const bf16x8*)&awg[nt * 1024 + lane * 8];
      bf1[nt] = *(const bf16x8*)&awg[nt * 1024 + 512 + lane * 8];
    }

    f32x4 acc[3][3];
#pragma unroll
    for (int mt = 0; mt < 3; mt++)
#pragma unroll
      for (int nt = 0; nt < 3; nt++) acc[mt][nt] = (f32x4){0.f, 0.f, 0.f, 0.f};

#pragma unroll
    for (int mt = 0; mt < 3; mt++) {
      bf16x8 a0 = *(const bf16x8*)&vA[(vrow0 + mt * 16 + lr) * 72 + lg * 8];
      bf16x8 a1 = *(const bf16x8*)&vA[(vrow0 + mt * 16 + lr) * 72 + 32 + lg * 8];
#pragma unroll
      for (int nt = 0; nt < 3; nt++) {
        acc[mt][nt] = __builtin_amdgcn_mfma_f32_16x16x32_bf16(a0, bf0[nt], acc[mt][nt], 0, 0, 0);
        acc[mt][nt] = __builtin_amdgcn_mfma_f32_16x16x32_bf16(a1, bf1[nt], acc[mt][nt], 0, 0, 0);
      }
    }

    float pv[3];
#pragma unroll
    for (int nt = 0; nt < 3; nt++) {
      float p = 0.f;
#pragma unroll
      for (int mt = 0; mt < 3; mt++) {
        short4 s = *(const short4*)&arg[(nt * 3 + mt) * 256 + lane * 4];
        p += bf2f((u16)s.x) * acc[mt][nt][0] + bf2f((u16)s.y) * acc[mt][nt][1]
           + bf2f((u16)s.z) * acc[mt][nt][2] + bf2f((u16)s.w) * acc[mt][nt][3];
      }
      p += __shfl_xor(p, 16);
      p += __shfl_xor(p, 32);
      pv[nt] = p;
    }

    if (lane < 48) {
      float a = (lane < 16) ? pv[0] : (lane < 32 ? pv[1] : pv[2]);
      a += pb;
      int ww = lane;
#pragma unroll
      for (int kh = -1; kh <= 1; kh++) {
        int ih = h + kh;
        if (ih < 0 || ih > 47) continue;
#pragma unroll
        for (int kw = -1; kw <= 1; kw++) {
          int jw = ww + kw;
          if (jw < 0 || jw > 47) continue;
          a += pw[(kh + 1) * 3 + (kw + 1)] * bf2f(vA[(vrow0 + ih) * 72 + jw]);
        }
      }
      u16 hh16 = f2bf(a);
      u16 ll16 = f2bf(a - bf2f(hh16));
      yg[h * 48 + ww] = (u32)hh16 | ((u32)ll16 << 16);
    }
  }
}

// ---------------------------------------------------------------------------
extern "C" void kernel_launch(void* const* d_in, const int* in_sizes, int n_in,
                              void* d_out, int out_size, void* d_ws, size_t ws_size,
                              hipStream_t stream) {
  const float* x      = (const float*)d_in[0];
  const float* rcv_w  = (const float*)d_in[1];
  const float* rcv_b  = (const float*)d_in[2];
  const float* pe_w   = (const float*)d_in[3];
  const float* pe_b   = (const float*)d_in[4];
  const float* proj_w = (const float*)d_in[5];
  const float* proj_b = (const float*)d_in[6];
  float* out = (float*)d_out;

  char* ws = (char*)d_ws;
  u32*   qkvP = (u32*)ws;                          // 0          14,155,776 B
  u16*   arF = (u16*)(ws + 14155776);              //  7,077,888 B
  u16*   awF = (u16*)(ws + 21233664);              //  9,437,184 B
  u32*   yP  = (u32*)(ws + 30670848);              //  9,437,184 B (packed h|l)
  u16*   Whr = (u16*)(ws + 40108032);              //    393,216 B
  u16*   Wlr = (u16*)(ws + 40501248);              //    393,216 B
  u16*   Whp = (u16*)(ws + 40894464);              //    131,072 B
  u16*   Wlp = (u16*)(ws + 41025536);              //    131,072 B (end ~41.2 MB)

  prep_kernel<<<dim3(256), 256, 0, stream>>>(rcv_w, Whr, Wlr, proj_w, Whp, Wlp);
  gemm_qkv_kernel<<<dim3(1728), 256, 0, stream>>>(Whr, Wlr, rcv_b, x, qkvP);
  scores_kernel<<<dim3(1024), 256, 0, stream>>>(qkvP, arF, awF);
  attn_main_kernel<<<dim3(2048), 256, 0, stream>>>(qkvP, arF, awF, pe_w, pe_b, yP);
  gemm_n64_kernel<<<dim3(576), 256, 0, stream>>>(Whp, Wlp, proj_b, yP, out);
}

// Round 23
// 95.284 us; speedup vs baseline: 1.0395x; 1.0395x over previous
//
#include <hip/hip_runtime.h>

#define S_ 2304   // 48*48

typedef unsigned short u16;
typedef unsigned int u32;
typedef __attribute__((ext_vector_type(8))) short bf16x8;
typedef __attribute__((ext_vector_type(4))) float f32x4;

static __device__ __forceinline__ u16 f2bf(float x) {
  union { float f; unsigned u; } v; v.f = x;
  unsigned r = v.u + 0x7FFFu + ((v.u >> 16) & 1u);
  return (u16)(r >> 16);
}
static __device__ __forceinline__ float bf2f(u16 h) {
  union { unsigned u; float f; } v; v.u = ((unsigned)h) << 16; return v.f;
}
static __device__ __forceinline__ float bflo(unsigned p) {
  union { unsigned u; float f; } v; v.u = p << 16; return v.f;
}
static __device__ __forceinline__ float bfhi(unsigned p) {
  union { unsigned u; float f; } v; v.u = p & 0xFFFF0000u; return v.f;
}

// Inline W split: fp32 -> h/l bf16 LDS tiles (replaces prep_kernel).
// Per kstep each block reads 64x32 fp32 (coalesced 16B/thread x2 reps);
// convert cost ~6 VALU / 4 elems. L2 traffic identical to pre-split bf16.
#define STAGE_W_SPLIT(Wf, t, buf)                                            \
  {                                                                          \
    _Pragma("unroll")                                                        \
    for (int r = 0; r < 2; r++) {                                            \
      int id = tid + r * 256;                                                \
      int m = id >> 3, k4 = (id & 7) * 4;                                    \
      float4 wv4 = *(const float4*)&Wf[(size_t)(m0 + m) * 256 + (t) * 32 + k4]; \
      float wf0 = wv4.x, wf1 = wv4.y, wf2 = wv4.z, wf3 = wv4.w;              \
      short4 hh4, ll4;                                                       \
      u16 ht;                                                                \
      ht = f2bf(wf0); hh4.x = (short)ht; ll4.x = (short)f2bf(wf0 - bf2f(ht)); \
      ht = f2bf(wf1); hh4.y = (short)ht; ll4.y = (short)f2bf(wf1 - bf2f(ht)); \
      ht = f2bf(wf2); hh4.z = (short)ht; ll4.z = (short)f2bf(wf2 - bf2f(ht)); \
      ht = f2bf(wf3); hh4.w = (short)ht; ll4.w = (short)f2bf(wf3 - bf2f(ht)); \
      *(short4*)&wAh[buf][m * 40 + k4] = hh4;                                \
      *(short4*)&wAl[buf][m * 40 + k4] = ll4;                                \
    }                                                                        \
  }

// ---------------------------------------------------------------------------
// QKV GEMM: Out = (Wh+Wl)*bf16(x), M=768, BN=64, 1728 blocks. W split inline
// from fp32 (prep_kernel deleted). B direct from x fp32 (r22-proven).
// Epilogue writes PAIR-PACKED bf16 qkvP.
// ---------------------------------------------------------------------------
__global__ __launch_bounds__(256) void gemm_qkv_kernel(
    const float* __restrict__ Wf, const float* __restrict__ bias,
    const float* __restrict__ x, u32* __restrict__ qkvP)
{
  __shared__ u16 wAh[2][64 * 40];
  __shared__ u16 wAl[2][64 * 40];
  const int MB = 12;
  const int xcd = blockIdx.x & 7;
  const int idx = blockIdx.x >> 3;          // 0..215
  const int g = xcd * 18 + idx / MB;        // 0..143 = (nb, b)
  const int mb = idx % MB;
  const int nb = g % 36, b = g / 36;
  const int m0 = mb * 64, n0 = nb * 64;
  const int tid = threadIdx.x;
  const int wv = tid >> 6, lane = tid & 63;
  const int wm = wv >> 1, wsd = wv & 1;
  const int lr = lane & 15, lg = lane >> 4;

  const float* xb = x + (size_t)b * 256 * S_;
  const int s0 = n0 + wsd * 32;

  f32x4 acc[2][2];
#pragma unroll
  for (int mt = 0; mt < 2; mt++)
#pragma unroll
    for (int nt = 0; nt < 2; nt++) acc[mt][nt] = (f32x4){0.f, 0.f, 0.f, 0.f};

#define LOAD_B(t, dst)                                                       \
  {                                                                          \
    _Pragma("unroll")                                                        \
    for (int nt = 0; nt < 2; nt++) {                                         \
      int s = s0 + nt * 16 + lr;                                             \
      _Pragma("unroll")                                                      \
      for (int e = 0; e < 8; e++)                                            \
        dst[nt][e] = (short)f2bf(xb[(size_t)((t) * 32 + lg * 8 + e) * S_ + s]); \
    }                                                                        \
  }

  STAGE_W_SPLIT(Wf, 0, 0);
  bf16x8 cb[2];
  LOAD_B(0, cb);
  __syncthreads();

  for (int t = 0; t < 8; t++) {
    int buf = t & 1;
    if (t < 7) STAGE_W_SPLIT(Wf, t + 1, buf ^ 1);

    bf16x8 nbv[2];
    if (t < 7) {
      LOAD_B(t + 1, nbv);
    } else {
#pragma unroll
      for (int nt = 0; nt < 2; nt++)
#pragma unroll
        for (int e = 0; e < 8; e++) nbv[nt][e] = 0;
    }

    bf16x8 ah[2], al[2];
#pragma unroll
    for (int mt = 0; mt < 2; mt++) {
      ah[mt] = *(const bf16x8*)&wAh[buf][(wm * 32 + mt * 16 + lr) * 40 + lg * 8];
      al[mt] = *(const bf16x8*)&wAl[buf][(wm * 32 + mt * 16 + lr) * 40 + lg * 8];
    }
#pragma unroll
    for (int mt = 0; mt < 2; mt++)
#pragma unroll
      for (int nt = 0; nt < 2; nt++) {
        acc[mt][nt] = __builtin_amdgcn_mfma_f32_16x16x32_bf16(ah[mt], cb[nt], acc[mt][nt], 0, 0, 0);
        acc[mt][nt] = __builtin_amdgcn_mfma_f32_16x16x32_bf16(al[mt], cb[nt], acc[mt][nt], 0, 0, 0);
      }
    __syncthreads();
#pragma unroll
    for (int nt = 0; nt < 2; nt++) cb[nt] = nbv[nt];
  }

  // epilogue: pack pairs of consecutive planes into u32 (r18 layout)
#pragma unroll
  for (int mt = 0; mt < 2; mt++) {
    int mb_ = m0 + wm * 32 + mt * 16 + lg * 4;   // 4 consecutive planes
    float4 b4 = *(const float4*)&bias[mb_];
    int head = mb_ / 96, pl = mb_ % 96;
    size_t rowoff = ((size_t)(b * 8 + head) * 48 + (pl >> 1)) * S_;
#pragma unroll
    for (int nt = 0; nt < 2; nt++) {
      int s = s0 + nt * 16 + lr;
      u16 h0 = f2bf(acc[mt][nt][0] + b4.x);
      u16 h1 = f2bf(acc[mt][nt][1] + b4.y);
      u16 h2 = f2bf(acc[mt][nt][2] + b4.z);
      u16 h3 = f2bf(acc[mt][nt][3] + b4.w);
      qkvP[rowoff + s]      = (u32)h0 | ((u32)h1 << 16);
      qkvP[rowoff + S_ + s] = (u32)h2 | ((u32)h3 << 16);
    }
  }
#undef LOAD_B
}

// ---------------------------------------------------------------------------
// Proj GEMM: BN=64, 576 blocks, W split inline from fp32, B direct from
// packed yP (r21-proven). 3-term split.
// ---------------------------------------------------------------------------
__global__ __launch_bounds__(256) void gemm_n64_kernel(
    const float* __restrict__ Wf, const float* __restrict__ bias,
    const u32* __restrict__ yP, float* __restrict__ Out)
{
  __shared__ u16 wAh[2][64 * 40];
  __shared__ u16 wAl[2][64 * 40];
  const int M = 256, MB = 4;
  const int xcd = blockIdx.x & 7;
  const int idx = blockIdx.x >> 3;
  const int g = xcd * 18 + idx / MB;
  const int mb = idx % MB;
  const int nb = g % 36, b = g / 36;
  const int m0 = mb * 64, n0 = nb * 64;
  const int tid = threadIdx.x;
  const int wv = tid >> 6, lane = tid & 63;
  const int wm = wv >> 1, wsd = wv & 1;
  const int lr = lane & 15, lg = lane >> 4;

  const u32* yb = yP + (size_t)b * 256 * S_;
  const int s0 = n0 + wsd * 32;

  f32x4 acc[2][2];
#pragma unroll
  for (int mt = 0; mt < 2; mt++)
#pragma unroll
    for (int nt = 0; nt < 2; nt++) acc[mt][nt] = (f32x4){0.f, 0.f, 0.f, 0.f};

#define LOAD_B(t, dst)                                                       \
  {                                                                          \
    _Pragma("unroll")                                                        \
    for (int nt = 0; nt < 2; nt++) {                                         \
      int s = s0 + nt * 16 + lr;                                             \
      _Pragma("unroll")                                                      \
      for (int e = 0; e < 8; e++)                                            \
        dst[nt][e] = yb[(size_t)((t) * 32 + lg * 8 + e) * S_ + s];           \
    }                                                                        \
  }

  STAGE_W_SPLIT(Wf, 0, 0);
  u32 cb[2][8];
  LOAD_B(0, cb);
  __syncthreads();

  for (int t = 0; t < 8; t++) {
    int buf = t & 1;
    if (t < 7) STAGE_W_SPLIT(Wf, t + 1, buf ^ 1);

    u32 nbv[2][8];
    if (t < 7) {
      LOAD_B(t + 1, nbv);
    } else {
#pragma unroll
      for (int nt = 0; nt < 2; nt++)
#pragma unroll
        for (int e = 0; e < 8; e++) nbv[nt][e] = 0;
    }

    bf16x8 ah[2], al[2];
#pragma unroll
    for (int mt = 0; mt < 2; mt++) {
      ah[mt] = *(const bf16x8*)&wAh[buf][(wm * 32 + mt * 16 + lr) * 40 + lg * 8];
      al[mt] = *(const bf16x8*)&wAl[buf][(wm * 32 + mt * 16 + lr) * 40 + lg * 8];
    }
    bf16x8 bh[2], bl[2];
#pragma unroll
    for (int nt = 0; nt < 2; nt++)
#pragma unroll
      for (int e = 0; e < 8; e++) {
        bh[nt][e] = (short)(cb[nt][e] & 0xffffu);
        bl[nt][e] = (short)(cb[nt][e] >> 16);
      }
#pragma unroll
    for (int mt = 0; mt < 2; mt++)
#pragma unroll
      for (int nt = 0; nt < 2; nt++) {
        acc[mt][nt] = __builtin_amdgcn_mfma_f32_16x16x32_bf16(ah[mt], bh[nt], acc[mt][nt], 0, 0, 0);
        acc[mt][nt] = __builtin_amdgcn_mfma_f32_16x16x32_bf16(ah[mt], bl[nt], acc[mt][nt], 0, 0, 0);
        acc[mt][nt] = __builtin_amdgcn_mfma_f32_16x16x32_bf16(al[mt], bh[nt], acc[mt][nt], 0, 0, 0);
      }
    __syncthreads();
#pragma unroll
    for (int nt = 0; nt < 2; nt++)
#pragma unroll
      for (int e = 0; e < 8; e++) cb[nt][e] = nbv[nt][e];
  }

  float* ob = Out + (size_t)b * M * S_;
#pragma unroll
  for (int mt = 0; mt < 2; mt++) {
    float4 b4 = *(const float4*)&bias[m0 + wm * 32 + mt * 16 + lg * 4];
    float bv[4] = {b4.x, b4.y, b4.z, b4.w};
#pragma unroll
    for (int nt = 0; nt < 2; nt++) {
      int s = n0 + wsd * 32 + nt * 16 + lr;
#pragma unroll
      for (int r = 0; r < 4; r++) {
        int m = m0 + wm * 32 + mt * 16 + lg * 4 + r;
        ob[(size_t)m * S_ + s] = acc[mt][nt][r] + bv[r];
      }
    }
  }
#undef LOAD_B
}

// ---------------------------------------------------------------------------
// Scores (r22-proven): packed u32 operands, dbuf, no-max softmax, 1024 blocks.
// ---------------------------------------------------------------------------
__global__ __launch_bounds__(256) void scores_kernel(
    const u32* __restrict__ qkv, u16* __restrict__ arF, u16* __restrict__ awF)
{
  __shared__ float Sm[2][48 * 49];
  __shared__ float red1[2][48];
  __shared__ u32 rkp[2][8 * 48];
  __shared__ u32 cqp[2][8 * 48], ckp[2][8 * 48];
  const int bid = blockIdx.x;
  const int tid = threadIdx.x;

  if (bid < 512) {
    // ---------------- ROW ----------------
    const int hg = bid & 15, n = (bid >> 4) & 7, b = bid >> 7;
    const u32* base = qkv + (size_t)(b * 8 + n) * 48 * S_;
    u32 rqp[9][8];
#pragma unroll
    for (int k = 0; k < 9; k++) {
      int p = tid + k * 256;
#pragma unroll
      for (int d8 = 0; d8 < 8; d8++)
        rqp[k][d8] = base[(size_t)d8 * S_ + p];
    }
    {
      int h = hg * 3;
      for (int id = tid; id < 384; id += 256)
        rkp[0][id] = base[(size_t)(8 + id / 48) * S_ + h * 48 + (id % 48)];
    }
    __syncthreads();
    for (int hh = 0; hh < 3; hh++) {
      const int buf = hh & 1;
      const int h = hg * 3 + hh;
#pragma unroll
      for (int k = 0; k < 9; k++) {
        int p = tid + k * 256;
        int i = p / 48, w = p % 48;
        float s = 0.f;
#pragma unroll
        for (int d8 = 0; d8 < 8; d8++) {
          u32 a = rqp[k][d8], c = rkp[buf][d8 * 48 + w];
          s += bflo(a) * bflo(c) + bfhi(a) * bfhi(c);
        }
        Sm[buf][i * 49 + w] = __expf(s * 0.25f);
      }
      if (hh < 2) {
        int hn = h + 1;
        for (int id = tid; id < 384; id += 256)
          rkp[buf ^ 1][id] = base[(size_t)(8 + id / 48) * S_ + hn * 48 + (id % 48)];
      }
      __syncthreads();
      if (tid < 192) {
        int w = tid >> 2, e = tid & 3;
        float s = 0.f;
        for (int i = e; i < 48; i += 4) s += Sm[buf][i * 49 + w];
        s += __shfl_xor(s, 1);
        s += __shfl_xor(s, 2);
        red1[buf][w] = 1.0f / s;
      }
      __syncthreads();
      u16* dst = arF + ((size_t)(b * 8 + n) * 48 + h) * 2304;
      for (int id = tid; id < 576; id += 256) {
        int nt = id / 192, rem = id % 192, mt = rem / 64, l = rem % 64;
        int w = nt * 16 + (l & 15);
        int i0 = mt * 16 + ((l >> 4) << 2);
        float rs = red1[buf][w];
        short4 o;
        o.x = (short)f2bf(Sm[buf][(i0 + 0) * 49 + w] * rs);
        o.y = (short)f2bf(Sm[buf][(i0 + 1) * 49 + w] * rs);
        o.z = (short)f2bf(Sm[buf][(i0 + 2) * 49 + w] * rs);
        o.w = (short)f2bf(Sm[buf][(i0 + 3) * 49 + w] * rs);
        *(short4*)&dst[id * 4] = o;
      }
    }
  } else {
    // ---------------- COL ----------------
    const int bid2 = bid - 512;
    const int hg = bid2 & 15, n = (bid2 >> 4) & 7, b = bid2 >> 7;
    const u32* base = qkv + (size_t)(b * 8 + n) * 48 * S_;
    {
      int h = hg * 3;
      for (int id = tid; id < 384; id += 256) {
        cqp[0][id] = base[(size_t)(16 + id / 48) * S_ + h * 48 + (id % 48)];
        ckp[0][id] = base[(size_t)(24 + id / 48) * S_ + h * 48 + (id % 48)];
      }
    }
    __syncthreads();
    for (int hh = 0; hh < 3; hh++) {
      const int buf = hh & 1;
      const int h = hg * 3 + hh;
      for (int id = tid; id < 2304; id += 256) {
        int w = id / 48, j = id % 48;
        float t = 0.f;
#pragma unroll
        for (int d8 = 0; d8 < 8; d8++) {
          u32 c = ckp[buf][d8 * 48 + w], a = cqp[buf][d8 * 48 + j];
          t += bflo(c) * bflo(a) + bfhi(c) * bfhi(a);
        }
        Sm[buf][w * 49 + j] = __expf(t * 0.25f);
      }
      if (hh < 2) {
        int hn = h + 1;
        for (int id = tid; id < 384; id += 256) {
          cqp[buf ^ 1][id] = base[(size_t)(16 + id / 48) * S_ + hn * 48 + (id % 48)];
          ckp[buf ^ 1][id] = base[(size_t)(24 + id / 48) * S_ + hn * 48 + (id % 48)];
        }
      }
      __syncthreads();
      if (tid < 192) {
        int w = tid >> 2, e = tid & 3;
        float s = 0.f;
        for (int j = e; j < 48; j += 4) s += Sm[buf][w * 49 + j];
        s += __shfl_xor(s, 1);
        s += __shfl_xor(s, 2);
        red1[buf][w] = 1.0f / s;
      }
      __syncthreads();
      u16* dst = awF + ((size_t)(b * 8 + n) * 48 + h) * 3072;
      for (int id = tid; id < 384; id += 256) {
        int nt = id / 128, rem = id % 128, ks = rem / 64, l = rem % 64;
        int w = nt * 16 + (l & 15);
        int j0 = ks * 32 + ((l >> 4) << 3);
        float rs = red1[buf][w];
        u16 t8[8];
#pragma unroll
        for (int e = 0; e < 8; e++) {
          int j = j0 + e;
          t8[e] = (j < 48) ? f2bf(Sm[buf][w * 49 + j] * rs) : (u16)0;
        }
        short4 o0, o1;
        o0.x = (short)t8[0]; o0.y = (short)t8[1]; o0.z = (short)t8[2]; o0.w = (short)t8[3];
        o1.x = (short)t8[4]; o1.y = (short)t8[5]; o1.z = (short)t8[6]; o1.w = (short)t8[7];
        *(short4*)&dst[id * 8]     = o0;
        *(short4*)&dst[id * 8 + 4] = o1;
      }
    }
  }
}

// ---------------------------------------------------------------------------
// Main contraction + PE conv (r21-proven, unchanged): packed-v staging,
// packed h|l yP epilogue.
// ---------------------------------------------------------------------------
__global__ __launch_bounds__(256) void attn_main_kernel(
    const u32* __restrict__ qkv, const u16* __restrict__ arF,
    const u16* __restrict__ awF, const float* __restrict__ pe_w,
    const float* __restrict__ pe_b, u32* __restrict__ yP)
{
  __shared__ u16 vA[96 * 72];         // 13824 B
  const int id0 = blockIdx.x;
  const int n = id0 & 7;              // XCD swizzle
  const int rest = id0 >> 3;          // 0..255
  const int b = rest >> 6;
  const int inner = rest & 63;
  const int dchunk = inner >> 2;      // 0..15 (one v-pair each)
  const int hc = inner & 3;
  const int tid = threadIdx.x;
  const int wave = tid >> 6, lane = tid & 63;
  const int dl = wave >> 1, half = wave & 1;
  const int h0 = hc * 12 + half * 6;
  const int lr = lane & 15, lg = lane >> 4;

  for (int id = tid; id < 96 * 24; id += 256) {
    int row = id / 24, col = 48 + id % 24;
    vA[row * 72 + col] = 0;
  }
  const u32* vrow = qkv + ((size_t)(b * 8 + n) * 48 + 32 + dchunk) * S_;
  for (int id = tid; id < 576; id += 256) {
    int i = id / 12, j4 = (id % 12) * 4;
    uint4 v = *(const uint4*)&vrow[i * 48 + j4];
    short4 lo, hi;
    lo.x = (short)(v.x & 0xffff); hi.x = (short)(v.x >> 16);
    lo.y = (short)(v.y & 0xffff); hi.y = (short)(v.y >> 16);
    lo.z = (short)(v.z & 0xffff); hi.z = (short)(v.z >> 16);
    lo.w = (short)(v.w & 0xffff); hi.w = (short)(v.w >> 16);
    *(short4*)&vA[i * 72 + j4] = lo;
    *(short4*)&vA[(48 + i) * 72 + j4] = hi;
  }
  __syncthreads();   // the only barrier

  const size_t bn48 = (size_t)(b * 8 + n) * 48;
  const int c = n * 32 + dchunk * 2 + dl;
  float pw[9];
#pragma unroll
  for (int t = 0; t < 9; t++) pw[t] = pe_w[c * 9 + t];
  const float pb = pe_b[c];
  u32* yg = yP + ((size_t)b * 256 + c) * S_;
  const int vrow0 = dl * 48;

  for (int hh = 0; hh < 6; hh++) {
    int h = h0 + hh;
    const u16* awg = awF + (bn48 + h) * 3072;
    const u16* arg = arF + (bn48 + h) * 2304;

    bf16x8 bf0[3], bf1[3];
#pragma unroll
    for (int nt = 0; nt < 3; nt++) {
      bf0[nt] = *(const bf16x8*)&awg[nt * 1024 + lane * 8];
      bf1[nt] = *(const bf16x8*)&awg[nt * 1024 + 512 + lane * 8];
    }

    f32x4 acc[3][3];
#pragma unroll
    for (int mt = 0; mt < 3; mt++)
#pragma unroll
      for (int nt = 0; nt < 3; nt++) acc[mt][nt] = (f32x4){0.f, 0.f, 0.f, 0.f};

#pragma unroll
    for (int mt = 0; mt < 3; mt++) {
      bf16x8 a0 = *(const bf16x8*)&vA[(vrow0 + mt * 16 + lr) * 72 + lg * 8];
      bf16x8 a1 = *(const bf16x8*)&vA[(vrow0 + mt * 16 + lr) * 72 + 32 + lg * 8];
#pragma unroll
      for (int nt = 0; nt < 3; nt++) {
        acc[mt][nt] = __builtin_amdgcn_mfma_f32_16x16x32_bf16(a0, bf0[nt], acc[mt][nt], 0, 0, 0);
        acc[mt][nt] = __builtin_amdgcn_mfma_f32_16x16x32_bf16(a1, bf1[nt], acc[mt][nt], 0, 0, 0);
      }
    }

    float pv[3];
#pragma unroll
    for (int nt = 0; nt < 3; nt++) {
      float p = 0.f;
#pragma unroll
      for (int mt = 0; mt < 3; mt++) {
        short4 s = *(const short4*)&arg[(nt * 3 + mt) * 256 + lane * 4];
        p += bf2f((u16)s.x) * acc[mt][nt][0] + bf2f((u16)s.y) * acc[mt][nt][1]
           + bf2f((u16)s.z) * acc[mt][nt][2] + bf2f((u16)s.w) * acc[mt][nt][3];
      }
      p += __shfl_xor(p, 16);
      p += __shfl_xor(p, 32);
      pv[nt] = p;
    }

    if (lane < 48) {
      float a = (lane < 16) ? pv[0] : (lane < 32 ? pv[1] : pv[2]);
      a += pb;
      int ww = lane;
#pragma unroll
      for (int kh = -1; kh <= 1; kh++) {
        int ih = h + kh;
        if (ih < 0 || ih > 47) continue;
#pragma unroll
        for (int kw = -1; kw <= 1; kw++) {
          int jw = ww + kw;
          if (jw < 0 || jw > 47) continue;
          a += pw[(kh + 1) * 3 + (kw + 1)] * bf2f(vA[(vrow0 + ih) * 72 + jw]);
        }
      }
      u16 hh16 = f2bf(a);
      u16 ll16 = f2bf(a - bf2f(hh16));
      yg[h * 48 + ww] = (u32)hh16 | ((u32)ll16 << 16);
    }
  }
}

// ---------------------------------------------------------------------------
extern "C" void kernel_launch(void* const* d_in, const int* in_sizes, int n_in,
                              void* d_out, int out_size, void* d_ws, size_t ws_size,
                              hipStream_t stream) {
  const float* x      = (const float*)d_in[0];
  const float* rcv_w  = (const float*)d_in[1];
  const float* rcv_b  = (const float*)d_in[2];
  const float* pe_w   = (const float*)d_in[3];
  const float* pe_b   = (const float*)d_in[4];
  const float* proj_w = (const float*)d_in[5];
  const float* proj_b = (const float*)d_in[6];
  float* out = (float*)d_out;

  char* ws = (char*)d_ws;
  u32*   qkvP = (u32*)ws;                          // 0          14,155,776 B
  u16*   arF = (u16*)(ws + 14155776);              //  7,077,888 B
  u16*   awF = (u16*)(ws + 21233664);              //  9,437,184 B
  u32*   yP  = (u32*)(ws + 30670848);              //  9,437,184 B (end ~40.1 MB)

  gemm_qkv_kernel<<<dim3(1728), 256, 0, stream>>>(rcv_w, rcv_b, x, qkvP);
  scores_kernel<<<dim3(1024), 256, 0, stream>>>(qkvP, arF, awF);
  attn_main_kernel<<<dim3(2048), 256, 0, stream>>>(qkvP, arF, awF, pe_w, pe_b, yP);
  gemm_n64_kernel<<<dim3(576), 256, 0, stream>>>(proj_w, proj_b, yP, out);
}

// Round 24
// 94.362 us; speedup vs baseline: 1.0496x; 1.0098x over previous
//
#include <hip/hip_runtime.h>

#define S_ 2304   // 48*48

typedef unsigned short u16;
typedef unsigned int u32;
typedef __attribute__((ext_vector_type(8))) short bf16x8;
typedef __attribute__((ext_vector_type(4))) float f32x4;

static __device__ __forceinline__ u16 f2bf(float x) {
  union { float f; unsigned u; } v; v.f = x;
  unsigned r = v.u + 0x7FFFu + ((v.u >> 16) & 1u);
  return (u16)(r >> 16);
}
static __device__ __forceinline__ float bf2f(u16 h) {
  union { unsigned u; float f; } v; v.u = ((unsigned)h) << 16; return v.f;
}
static __device__ __forceinline__ float bflo(unsigned p) {
  union { unsigned u; float f; } v; v.u = p << 16; return v.f;
}
static __device__ __forceinline__ float bfhi(unsigned p) {
  union { unsigned u; float f; } v; v.u = p & 0xFFFF0000u; return v.f;
}

// Inline W split: fp32 -> h/l bf16 LDS tiles (r23-proven).
#define STAGE_W_SPLIT(Wf, t, buf)                                            \
  {                                                                          \
    _Pragma("unroll")                                                        \
    for (int r = 0; r < 2; r++) {                                            \
      int id = tid + r * 256;                                                \
      int m = id >> 3, k4 = (id & 7) * 4;                                    \
      float4 wv4 = *(const float4*)&Wf[(size_t)(m0 + m) * 256 + (t) * 32 + k4]; \
      float wf0 = wv4.x, wf1 = wv4.y, wf2 = wv4.z, wf3 = wv4.w;              \
      short4 hh4, ll4;                                                       \
      u16 ht;                                                                \
      ht = f2bf(wf0); hh4.x = (short)ht; ll4.x = (short)f2bf(wf0 - bf2f(ht)); \
      ht = f2bf(wf1); hh4.y = (short)ht; ll4.y = (short)f2bf(wf1 - bf2f(ht)); \
      ht = f2bf(wf2); hh4.z = (short)ht; ll4.z = (short)f2bf(wf2 - bf2f(ht)); \
      ht = f2bf(wf3); hh4.w = (short)ht; ll4.w = (short)f2bf(wf3 - bf2f(ht)); \
      *(short4*)&wAh[buf][m * 40 + k4] = hh4;                                \
      *(short4*)&wAl[buf][m * 40 + k4] = ll4;                                \
    }                                                                        \
  }

// ---------------------------------------------------------------------------
// QKV GEMM (r23-proven): Out = (Wh+Wl)*bf16(x), M=768, BN=64, 1728 blocks.
// W split inline; B direct from x fp32; epilogue writes PAIR-PACKED qkvP.
// ---------------------------------------------------------------------------
__global__ __launch_bounds__(256) void gemm_qkv_kernel(
    const float* __restrict__ Wf, const float* __restrict__ bias,
    const float* __restrict__ x, u32* __restrict__ qkvP)
{
  __shared__ u16 wAh[2][64 * 40];
  __shared__ u16 wAl[2][64 * 40];
  const int MB = 12;
  const int xcd = blockIdx.x & 7;
  const int idx = blockIdx.x >> 3;          // 0..215
  const int g = xcd * 18 + idx / MB;        // 0..143 = (nb, b)
  const int mb = idx % MB;
  const int nb = g % 36, b = g / 36;
  const int m0 = mb * 64, n0 = nb * 64;
  const int tid = threadIdx.x;
  const int wv = tid >> 6, lane = tid & 63;
  const int wm = wv >> 1, wsd = wv & 1;
  const int lr = lane & 15, lg = lane >> 4;

  const float* xb = x + (size_t)b * 256 * S_;
  const int s0 = n0 + wsd * 32;

  f32x4 acc[2][2];
#pragma unroll
  for (int mt = 0; mt < 2; mt++)
#pragma unroll
    for (int nt = 0; nt < 2; nt++) acc[mt][nt] = (f32x4){0.f, 0.f, 0.f, 0.f};

#define LOAD_B(t, dst)                                                       \
  {                                                                          \
    _Pragma("unroll")                                                        \
    for (int nt = 0; nt < 2; nt++) {                                         \
      int s = s0 + nt * 16 + lr;                                             \
      _Pragma("unroll")                                                      \
      for (int e = 0; e < 8; e++)                                            \
        dst[nt][e] = (short)f2bf(xb[(size_t)((t) * 32 + lg * 8 + e) * S_ + s]); \
    }                                                                        \
  }

  STAGE_W_SPLIT(Wf, 0, 0);
  bf16x8 cb[2];
  LOAD_B(0, cb);
  __syncthreads();

  for (int t = 0; t < 8; t++) {
    int buf = t & 1;
    if (t < 7) STAGE_W_SPLIT(Wf, t + 1, buf ^ 1);

    bf16x8 nbv[2];
    if (t < 7) {
      LOAD_B(t + 1, nbv);
    } else {
#pragma unroll
      for (int nt = 0; nt < 2; nt++)
#pragma unroll
        for (int e = 0; e < 8; e++) nbv[nt][e] = 0;
    }

    bf16x8 ah[2], al[2];
#pragma unroll
    for (int mt = 0; mt < 2; mt++) {
      ah[mt] = *(const bf16x8*)&wAh[buf][(wm * 32 + mt * 16 + lr) * 40 + lg * 8];
      al[mt] = *(const bf16x8*)&wAl[buf][(wm * 32 + mt * 16 + lr) * 40 + lg * 8];
    }
#pragma unroll
    for (int mt = 0; mt < 2; mt++)
#pragma unroll
      for (int nt = 0; nt < 2; nt++) {
        acc[mt][nt] = __builtin_amdgcn_mfma_f32_16x16x32_bf16(ah[mt], cb[nt], acc[mt][nt], 0, 0, 0);
        acc[mt][nt] = __builtin_amdgcn_mfma_f32_16x16x32_bf16(al[mt], cb[nt], acc[mt][nt], 0, 0, 0);
      }
    __syncthreads();
#pragma unroll
    for (int nt = 0; nt < 2; nt++) cb[nt] = nbv[nt];
  }

#pragma unroll
  for (int mt = 0; mt < 2; mt++) {
    int mb_ = m0 + wm * 32 + mt * 16 + lg * 4;
    float4 b4 = *(const float4*)&bias[mb_];
    int head = mb_ / 96, pl = mb_ % 96;
    size_t rowoff = ((size_t)(b * 8 + head) * 48 + (pl >> 1)) * S_;
#pragma unroll
    for (int nt = 0; nt < 2; nt++) {
      int s = s0 + nt * 16 + lr;
      u16 h0 = f2bf(acc[mt][nt][0] + b4.x);
      u16 h1 = f2bf(acc[mt][nt][1] + b4.y);
      u16 h2 = f2bf(acc[mt][nt][2] + b4.z);
      u16 h3 = f2bf(acc[mt][nt][3] + b4.w);
      qkvP[rowoff + s]      = (u32)h0 | ((u32)h1 << 16);
      qkvP[rowoff + S_ + s] = (u32)h2 | ((u32)h3 << 16);
    }
  }
#undef LOAD_B
}

// ---------------------------------------------------------------------------
// Proj GEMM (r23-proven): BN=64, W split inline, B direct from packed yP.
// ---------------------------------------------------------------------------
__global__ __launch_bounds__(256) void gemm_n64_kernel(
    const float* __restrict__ Wf, const float* __restrict__ bias,
    const u32* __restrict__ yP, float* __restrict__ Out)
{
  __shared__ u16 wAh[2][64 * 40];
  __shared__ u16 wAl[2][64 * 40];
  const int M = 256, MB = 4;
  const int xcd = blockIdx.x & 7;
  const int idx = blockIdx.x >> 3;
  const int g = xcd * 18 + idx / MB;
  const int mb = idx % MB;
  const int nb = g % 36, b = g / 36;
  const int m0 = mb * 64, n0 = nb * 64;
  const int tid = threadIdx.x;
  const int wv = tid >> 6, lane = tid & 63;
  const int wm = wv >> 1, wsd = wv & 1;
  const int lr = lane & 15, lg = lane >> 4;

  const u32* yb = yP + (size_t)b * 256 * S_;
  const int s0 = n0 + wsd * 32;

  f32x4 acc[2][2];
#pragma unroll
  for (int mt = 0; mt < 2; mt++)
#pragma unroll
    for (int nt = 0; nt < 2; nt++) acc[mt][nt] = (f32x4){0.f, 0.f, 0.f, 0.f};

#define LOAD_B(t, dst)                                                       \
  {                                                                          \
    _Pragma("unroll")                                                        \
    for (int nt = 0; nt < 2; nt++) {                                         \
      int s = s0 + nt * 16 + lr;                                             \
      _Pragma("unroll")                                                      \
      for (int e = 0; e < 8; e++)                                            \
        dst[nt][e] = yb[(size_t)((t) * 32 + lg * 8 + e) * S_ + s];           \
    }                                                                        \
  }

  STAGE_W_SPLIT(Wf, 0, 0);
  u32 cb[2][8];
  LOAD_B(0, cb);
  __syncthreads();

  for (int t = 0; t < 8; t++) {
    int buf = t & 1;
    if (t < 7) STAGE_W_SPLIT(Wf, t + 1, buf ^ 1);

    u32 nbv[2][8];
    if (t < 7) {
      LOAD_B(t + 1, nbv);
    } else {
#pragma unroll
      for (int nt = 0; nt < 2; nt++)
#pragma unroll
        for (int e = 0; e < 8; e++) nbv[nt][e] = 0;
    }

    bf16x8 ah[2], al[2];
#pragma unroll
    for (int mt = 0; mt < 2; mt++) {
      ah[mt] = *(const bf16x8*)&wAh[buf][(wm * 32 + mt * 16 + lr) * 40 + lg * 8];
      al[mt] = *(const bf16x8*)&wAl[buf][(wm * 32 + mt * 16 + lr) * 40 + lg * 8];
    }
    bf16x8 bh[2], bl[2];
#pragma unroll
    for (int nt = 0; nt < 2; nt++)
#pragma unroll
      for (int e = 0; e < 8; e++) {
        bh[nt][e] = (short)(cb[nt][e] & 0xffffu);
        bl[nt][e] = (short)(cb[nt][e] >> 16);
      }
#pragma unroll
    for (int mt = 0; mt < 2; mt++)
#pragma unroll
      for (int nt = 0; nt < 2; nt++) {
        acc[mt][nt] = __builtin_amdgcn_mfma_f32_16x16x32_bf16(ah[mt], bh[nt], acc[mt][nt], 0, 0, 0);
        acc[mt][nt] = __builtin_amdgcn_mfma_f32_16x16x32_bf16(ah[mt], bl[nt], acc[mt][nt], 0, 0, 0);
        acc[mt][nt] = __builtin_amdgcn_mfma_f32_16x16x32_bf16(al[mt], bh[nt], acc[mt][nt], 0, 0, 0);
      }
    __syncthreads();
#pragma unroll
    for (int nt = 0; nt < 2; nt++)
#pragma unroll
      for (int e = 0; e < 8; e++) cb[nt][e] = nbv[nt][e];
  }

  float* ob = Out + (size_t)b * M * S_;
#pragma unroll
  for (int mt = 0; mt < 2; mt++) {
    float4 b4 = *(const float4*)&bias[m0 + wm * 32 + mt * 16 + lg * 4];
    float bv[4] = {b4.x, b4.y, b4.z, b4.w};
#pragma unroll
    for (int nt = 0; nt < 2; nt++) {
      int s = n0 + wsd * 32 + nt * 16 + lr;
#pragma unroll
      for (int r = 0; r < 4; r++) {
        int m = m0 + wm * 32 + mt * 16 + lg * 4 + r;
        ob[(size_t)m * S_ + s] = acc[mt][nt][r] + bv[r];
      }
    }
  }
#undef LOAD_B
}

// ---------------------------------------------------------------------------
// Scores (r22 bodies) with XCD-COLOCATED decode: the 16 h-group blocks that
// re-read one (b,n)'s rq (73KB) / cq+ck panels now land on ONE XCD
// (xcd = bid&7; bn = xcd*4 + idx/16; hg = idx%16) instead of being spread
// round-robin over all 8 L2s.
// 1024 blocks: 0..511 ROW, 512..1023 COL.
// ---------------------------------------------------------------------------
__global__ __launch_bounds__(256) void scores_kernel(
    const u32* __restrict__ qkv, u16* __restrict__ arF, u16* __restrict__ awF)
{
  __shared__ float Sm[2][48 * 49];
  __shared__ float red1[2][48];
  __shared__ u32 rkp[2][8 * 48];
  __shared__ u32 cqp[2][8 * 48], ckp[2][8 * 48];
  const int bid = blockIdx.x;
  const int tid = threadIdx.x;

  if (bid < 512) {
    // ---------------- ROW ----------------
    const int xcd = bid & 7, idx = bid >> 3;        // idx 0..63
    const int bn = xcd * 4 + (idx >> 4);            // 0..31, colocated per XCD
    const int hg = idx & 15;
    const int b = bn >> 3, n = bn & 7;
    const u32* base = qkv + (size_t)(b * 8 + n) * 48 * S_;
    u32 rqp[9][8];
#pragma unroll
    for (int k = 0; k < 9; k++) {
      int p = tid + k * 256;
#pragma unroll
      for (int d8 = 0; d8 < 8; d8++)
        rqp[k][d8] = base[(size_t)d8 * S_ + p];
    }
    {
      int h = hg * 3;
      for (int id = tid; id < 384; id += 256)
        rkp[0][id] = base[(size_t)(8 + id / 48) * S_ + h * 48 + (id % 48)];
    }
    __syncthreads();
    for (int hh = 0; hh < 3; hh++) {
      const int buf = hh & 1;
      const int h = hg * 3 + hh;
#pragma unroll
      for (int k = 0; k < 9; k++) {
        int p = tid + k * 256;
        int i = p / 48, w = p % 48;
        float s = 0.f;
#pragma unroll
        for (int d8 = 0; d8 < 8; d8++) {
          u32 a = rqp[k][d8], c = rkp[buf][d8 * 48 + w];
          s += bflo(a) * bflo(c) + bfhi(a) * bfhi(c);
        }
        Sm[buf][i * 49 + w] = __expf(s * 0.25f);
      }
      if (hh < 2) {
        int hn = h + 1;
        for (int id = tid; id < 384; id += 256)
          rkp[buf ^ 1][id] = base[(size_t)(8 + id / 48) * S_ + hn * 48 + (id % 48)];
      }
      __syncthreads();
      if (tid < 192) {
        int w = tid >> 2, e = tid & 3;
        float s = 0.f;
        for (int i = e; i < 48; i += 4) s += Sm[buf][i * 49 + w];
        s += __shfl_xor(s, 1);
        s += __shfl_xor(s, 2);
        red1[buf][w] = 1.0f / s;
      }
      __syncthreads();
      u16* dst = arF + ((size_t)(b * 8 + n) * 48 + h) * 2304;
      for (int id = tid; id < 576; id += 256) {
        int nt = id / 192, rem = id % 192, mt = rem / 64, l = rem % 64;
        int w = nt * 16 + (l & 15);
        int i0 = mt * 16 + ((l >> 4) << 2);
        float rs = red1[buf][w];
        short4 o;
        o.x = (short)f2bf(Sm[buf][(i0 + 0) * 49 + w] * rs);
        o.y = (short)f2bf(Sm[buf][(i0 + 1) * 49 + w] * rs);
        o.z = (short)f2bf(Sm[buf][(i0 + 2) * 49 + w] * rs);
        o.w = (short)f2bf(Sm[buf][(i0 + 3) * 49 + w] * rs);
        *(short4*)&dst[id * 4] = o;
      }
    }
  } else {
    // ---------------- COL ----------------
    const int bid2 = bid - 512;
    const int xcd = bid2 & 7, idx = bid2 >> 3;
    const int bn = xcd * 4 + (idx >> 4);
    const int hg = idx & 15;
    const int b = bn >> 3, n = bn & 7;
    const u32* base = qkv + (size_t)(b * 8 + n) * 48 * S_;
    {
      int h = hg * 3;
      for (int id = tid; id < 384; id += 256) {
        cqp[0][id] = base[(size_t)(16 + id / 48) * S_ + h * 48 + (id % 48)];
        ckp[0][id] = base[(size_t)(24 + id / 48) * S_ + h * 48 + (id % 48)];
      }
    }
    __syncthreads();
    for (int hh = 0; hh < 3; hh++) {
      const int buf = hh & 1;
      const int h = hg * 3 + hh;
      for (int id = tid; id < 2304; id += 256) {
        int w = id / 48, j = id % 48;
        float t = 0.f;
#pragma unroll
        for (int d8 = 0; d8 < 8; d8++) {
          u32 c = ckp[buf][d8 * 48 + w], a = cqp[buf][d8 * 48 + j];
          t += bflo(c) * bflo(a) + bfhi(c) * bfhi(a);
        }
        Sm[buf][w * 49 + j] = __expf(t * 0.25f);
      }
      if (hh < 2) {
        int hn = h + 1;
        for (int id = tid; id < 384; id += 256) {
          cqp[buf ^ 1][id] = base[(size_t)(16 + id / 48) * S_ + hn * 48 + (id % 48)];
          ckp[buf ^ 1][id] = base[(size_t)(24 + id / 48) * S_ + hn * 48 + (id % 48)];
        }
      }
      __syncthreads();
      if (tid < 192) {
        int w = tid >> 2, e = tid & 3;
        float s = 0.f;
        for (int j = e; j < 48; j += 4) s += Sm[buf][w * 49 + j];
        s += __shfl_xor(s, 1);
        s += __shfl_xor(s, 2);
        red1[buf][w] = 1.0f / s;
      }
      __syncthreads();
      u16* dst = awF + ((size_t)(b * 8 + n) * 48 + h) * 3072;
      for (int id = tid; id < 384; id += 256) {
        int nt = id / 128, rem = id % 128, ks = rem / 64, l = rem % 64;
        int w = nt * 16 + (l & 15);
        int j0 = ks * 32 + ((l >> 4) << 3);
        float rs = red1[buf][w];
        u16 t8[8];
#pragma unroll
        for (int e = 0; e < 8; e++) {
          int j = j0 + e;
          t8[e] = (j < 48) ? f2bf(Sm[buf][w * 49 + j] * rs) : (u16)0;
        }
        short4 o0, o1;
        o0.x = (short)t8[0]; o0.y = (short)t8[1]; o0.z = (short)t8[2]; o0.w = (short)t8[3];
        o1.x = (short)t8[4]; o1.y = (short)t8[5]; o1.z = (short)t8[6]; o1.w = (short)t8[7];
        *(short4*)&dst[id * 8]     = o0;
        *(short4*)&dst[id * 8 + 4] = o1;
      }
    }
  }
}

// ---------------------------------------------------------------------------
// Main contraction + PE conv (r21-proven, unchanged).
// ---------------------------------------------------------------------------
__global__ __launch_bounds__(256) void attn_main_kernel(
    const u32* __restrict__ qkv, const u16* __restrict__ arF,
    const u16* __restrict__ awF, const float* __restrict__ pe_w,
    const float* __restrict__ pe_b, u32* __restrict__ yP)
{
  __shared__ u16 vA[96 * 72];         // 13824 B
  const int id0 = blockIdx.x;
  const int n = id0 & 7;              // XCD swizzle
  const int rest = id0 >> 3;          // 0..255
  const int b = rest >> 6;
  const int inner = rest & 63;
  const int dchunk = inner >> 2;      // 0..15 (one v-pair each)
  const int hc = inner & 3;
  const int tid = threadIdx.x;
  const int wave = tid >> 6, lane = tid & 63;
  const int dl = wave >> 1, half = wave & 1;
  const int h0 = hc * 12 + half * 6;
  const int lr = lane & 15, lg = lane >> 4;

  for (int id = tid; id < 96 * 24; id += 256) {
    int row = id / 24, col = 48 + id % 24;
    vA[row * 72 + col] = 0;
  }
  const u32* vrow = qkv + ((size_t)(b * 8 + n) * 48 + 32 + dchunk) * S_;
  for (int id = tid; id < 576; id += 256) {
    int i = id / 12, j4 = (id % 12) * 4;
    uint4 v = *(const uint4*)&vrow[i * 48 + j4];
    short4 lo, hi;
    lo.x = (short)(v.x & 0xffff); hi.x = (short)(v.x >> 16);
    lo.y = (short)(v.y & 0xffff); hi.y = (short)(v.y >> 16);
    lo.z = (short)(v.z & 0xffff); hi.z = (short)(v.z >> 16);
    lo.w = (short)(v.w & 0xffff); hi.w = (short)(v.w >> 16);
    *(short4*)&vA[i * 72 + j4] = lo;
    *(short4*)&vA[(48 + i) * 72 + j4] = hi;
  }
  __syncthreads();   // the only barrier

  const size_t bn48 = (size_t)(b * 8 + n) * 48;
  const int c = n * 32 + dchunk * 2 + dl;
  float pw[9];
#pragma unroll
  for (int t = 0; t < 9; t++) pw[t] = pe_w[c * 9 + t];
  const float pb = pe_b[c];
  u32* yg = yP + ((size_t)b * 256 + c) * S_;
  const int vrow0 = dl * 48;

  for (int hh = 0; hh < 6; hh++) {
    int h = h0 + hh;
    const u16* awg = awF + (bn48 + h) * 3072;
    const u16* arg = arF + (bn48 + h) * 2304;

    bf16x8 bf0[3], bf1[3];
#pragma unroll
    for (int nt = 0; nt < 3; nt++) {
      bf0[nt] = *(const bf16x8*)&awg[nt * 1024 + lane * 8];
      bf1[nt] = *(const bf16x8*)&awg[nt * 1024 + 512 + lane * 8];
    }

    f32x4 acc[3][3];
#pragma unroll
    for (int mt = 0; mt < 3; mt++)
#pragma unroll
      for (int nt = 0; nt < 3; nt++) acc[mt][nt] = (f32x4){0.f, 0.f, 0.f, 0.f};

#pragma unroll
    for (int mt = 0; mt < 3; mt++) {
      bf16x8 a0 = *(const bf16x8*)&vA[(vrow0 + mt * 16 + lr) * 72 + lg * 8];
      bf16x8 a1 = *(const bf16x8*)&vA[(vrow0 + mt * 16 + lr) * 72 + 32 + lg * 8];
#pragma unroll
      for (int nt = 0; nt < 3; nt++) {
        acc[mt][nt] = __builtin_amdgcn_mfma_f32_16x16x32_bf16(a0, bf0[nt], acc[mt][nt], 0, 0, 0);
        acc[mt][nt] = __builtin_amdgcn_mfma_f32_16x16x32_bf16(a1, bf1[nt], acc[mt][nt], 0, 0, 0);
      }
    }

    float pv[3];
#pragma unroll
    for (int nt = 0; nt < 3; nt++) {
      float p = 0.f;
#pragma unroll
      for (int mt = 0; mt < 3; mt++) {
        short4 s = *(const short4*)&arg[(nt * 3 + mt) * 256 + lane * 4];
        p += bf2f((u16)s.x) * acc[mt][nt][0] + bf2f((u16)s.y) * acc[mt][nt][1]
           + bf2f((u16)s.z) * acc[mt][nt][2] + bf2f((u16)s.w) * acc[mt][nt][3];
      }
      p += __shfl_xor(p, 16);
      p += __shfl_xor(p, 32);
      pv[nt] = p;
    }

    if (lane < 48) {
      float a = (lane < 16) ? pv[0] : (lane < 32 ? pv[1] : pv[2]);
      a += pb;
      int ww = lane;
#pragma unroll
      for (int kh = -1; kh <= 1; kh++) {
        int ih = h + kh;
        if (ih < 0 || ih > 47) continue;
#pragma unroll
        for (int kw = -1; kw <= 1; kw++) {
          int jw = ww + kw;
          if (jw < 0 || jw > 47) continue;
          a += pw[(kh + 1) * 3 + (kw + 1)] * bf2f(vA[(vrow0 + ih) * 72 + jw]);
        }
      }
      u16 hh16 = f2bf(a);
      u16 ll16 = f2bf(a - bf2f(hh16));
      yg[h * 48 + ww] = (u32)hh16 | ((u32)ll16 << 16);
    }
  }
}

// ---------------------------------------------------------------------------
extern "C" void kernel_launch(void* const* d_in, const int* in_sizes, int n_in,
                              void* d_out, int out_size, void* d_ws, size_t ws_size,
                              hipStream_t stream) {
  const float* x      = (const float*)d_in[0];
  const float* rcv_w  = (const float*)d_in[1];
  const float* rcv_b  = (const float*)d_in[2];
  const float* pe_w   = (const float*)d_in[3];
  const float* pe_b   = (const float*)d_in[4];
  const float* proj_w = (const float*)d_in[5];
  const float* proj_b = (const float*)d_in[6];
  float* out = (float*)d_out;

  char* ws = (char*)d_ws;
  u32*   qkvP = (u32*)ws;                          // 0          14,155,776 B
  u16*   arF = (u16*)(ws + 14155776);              //  7,077,888 B
  u16*   awF = (u16*)(ws + 21233664);              //  9,437,184 B
  u32*   yP  = (u32*)(ws + 30670848);              //  9,437,184 B (end ~40.1 MB)

  gemm_qkv_kernel<<<dim3(1728), 256, 0, stream>>>(rcv_w, rcv_b, x, qkvP);
  scores_kernel<<<dim3(1024), 256, 0, stream>>>(qkvP, arF, awF);
  attn_main_kernel<<<dim3(2048), 256, 0, stream>>>(qkvP, arF, awF, pe_w, pe_b, yP);
  gemm_n64_kernel<<<dim3(576), 256, 0, stream>>>(proj_w, proj_b, yP, out);
}